// Round 1
// baseline (264.592 us; speedup 1.0000x reference)
//
#include <hip/hip_runtime.h>

typedef __attribute__((ext_vector_type(8))) short short8;
typedef __attribute__((ext_vector_type(4))) float f32x4;
typedef __attribute__((ext_vector_type(4))) unsigned short ushort4v;

__device__ __forceinline__ unsigned short f2bf(float f) {
  unsigned int u = __float_as_uint(f);
  u += 0x7fffu + ((u >> 16) & 1u);
  return (unsigned short)(u >> 16);
}
__device__ __forceinline__ float bf2f(unsigned short h) {
  return __uint_as_float(((unsigned int)h) << 16);
}

__device__ __forceinline__ void gload16(const unsigned short* g, unsigned short* l) {
  __builtin_amdgcn_global_load_lds(
      (const __attribute__((address_space(1))) unsigned int*)g,
      (__attribute__((address_space(3))) unsigned int*)l,
      16, 0, 0);
}

// ---------------- convert x (f32) -> bf16, same layout ----------------
__global__ __launch_bounds__(256) void conv_x_kernel(const float* __restrict__ x,
                                                     unsigned short* __restrict__ xb) {
  int i = blockIdx.x * 256 + threadIdx.x;
  f32x4 v = ((const f32x4*)x)[i];
  ushort4v o;
  o[0] = f2bf(v[0]); o[1] = f2bf(v[1]); o[2] = f2bf(v[2]); o[3] = f2bf(v[3]);
  ((ushort4v*)xb)[i] = o;
}

// ------------- transpose+convert W: f32 [K][N] -> bf16 [N][K] -------------
__global__ __launch_bounds__(256) void transpose_w_kernel(const float* __restrict__ W,
                                                          unsigned short* __restrict__ Wt,
                                                          int K, int N) {
  __shared__ float tile[32][33];
  int n0 = blockIdx.x * 32, k0 = blockIdx.y * 32;
  int tx = threadIdx.x, ty = threadIdx.y;
#pragma unroll
  for (int j = 0; j < 32; j += 8)
    tile[ty + j][tx] = W[(size_t)(k0 + ty + j) * N + n0 + tx];
  __syncthreads();
#pragma unroll
  for (int j = 0; j < 32; j += 8)
    Wt[(size_t)(n0 + ty + j) * K + k0 + tx] = f2bf(tile[tx][ty + j]);
}

// ------- transpose V (bf16 part of qkv) -> vt [B][1024][2048] -------
__global__ __launch_bounds__(256) void transpose_v_kernel(const unsigned short* __restrict__ qkv,
                                                          unsigned short* __restrict__ vt) {
  __shared__ unsigned short tile[32][33];
  int b = blockIdx.z;
  int key0 = blockIdx.x * 32, d0 = blockIdx.y * 32;
  int tx = threadIdx.x, ty = threadIdx.y;
#pragma unroll
  for (int j = 0; j < 32; j += 8)
    tile[ty + j][tx] = qkv[(size_t)(b * 2048 + key0 + ty + j) * 3072 + 2048 + d0 + tx];
  __syncthreads();
#pragma unroll
  for (int j = 0; j < 32; j += 8)
    vt[(size_t)(b * 1024 + d0 + ty + j) * 2048 + key0 + tx] = tile[tx][ty + j];
}

// ---------------- row softmax on S (bf16, in place), rows of length 2048 ---
__global__ __launch_bounds__(256) void softmax_kernel(unsigned short* __restrict__ S) {
  int row = blockIdx.x * 4 + (threadIdx.x >> 6);
  int l = threadIdx.x & 63;
  unsigned short* p = S + (size_t)row * 2048;
  float v[32];
#pragma unroll
  for (int i = 0; i < 4; i++) {
    short8 raw = *(const short8*)&p[(i * 64 + l) * 8];
#pragma unroll
    for (int j = 0; j < 8; j++) v[i * 8 + j] = bf2f((unsigned short)raw[j]);
  }
  float mx = -3e38f;
#pragma unroll
  for (int i = 0; i < 32; i++) mx = fmaxf(mx, v[i]);
#pragma unroll
  for (int off = 1; off < 64; off <<= 1) mx = fmaxf(mx, __shfl_xor(mx, off));
  float s = 0.f;
#pragma unroll
  for (int i = 0; i < 32; i++) { v[i] = exp2f((v[i] - mx) * 1.44269504f); s += v[i]; }
#pragma unroll
  for (int off = 1; off < 64; off <<= 1) s += __shfl_xor(s, off);
  float inv = 1.f / s;
#pragma unroll
  for (int i = 0; i < 4; i++) {
    short8 o;
#pragma unroll
    for (int j = 0; j < 8; j++) o[j] = (short)f2bf(v[i * 8 + j] * inv);
    *(short8*)&p[(i * 64 + l) * 8] = o;
  }
}

// ---------------- GEMM: C[M][N] = A[M][K] @ Bt[N][K]^T * scale + bias ------
// causal: 0 = none; 1 = causal-mask output (S = QK^T); 2 = K-loop truncated
// to m0+128 (PV, exact because masked P == 0).
template <int OUTBF>
__global__ __launch_bounds__(256) void gemm_bt_kernel(
    const unsigned short* __restrict__ A, int lda, long long saz,
    const unsigned short* __restrict__ Bt, int ldb, long long sbz,
    void* __restrict__ Cv, int ldc, long long scz,
    const float* __restrict__ bias, int K, float scale, int causal) {
  int m0 = blockIdx.y * 128, n0 = blockIdx.x * 128;
  int z = blockIdx.z;
  A += (size_t)z * saz;
  Bt += (size_t)z * sbz;
  int t = threadIdx.x;
  int l = t & 63, w = t >> 6;
  int g = l >> 4, q = l & 15;
  int wm = w >> 1, wn = w & 1;

  __shared__ __align__(16) unsigned short As[128 * 32];
  __shared__ __align__(16) unsigned short Bs[128 * 32];

  int kend = K;
  if (causal == 1) { if (n0 >= m0 + 128) kend = 0; }
  else if (causal == 2) { kend = min(K, m0 + 128); }

  f32x4 acc[4][4] = {};

  const unsigned short* aSrc = A + (size_t)(m0 + (t >> 2)) * lda + (t & 3) * 8;
  const unsigned short* bSrc = Bt + (size_t)(n0 + (t >> 2)) * ldb + (t & 3) * 8;
  unsigned short* aDst = As + w * 512;  // wave-uniform; HW adds lane*16B
  unsigned short* bDst = Bs + w * 512;

  for (int k0 = 0; k0 < kend; k0 += 32) {
    gload16(aSrc + k0, aDst);
    gload16(aSrc + (size_t)64 * lda + k0, aDst + 2048);
    gload16(bSrc + k0, bDst);
    gload16(bSrc + (size_t)64 * ldb + k0, bDst + 2048);
    __syncthreads();
    short8 af[4], bfr[4];
#pragma unroll
    for (int m = 0; m < 4; m++)
      af[m] = *(const short8*)&As[(wm * 64 + m * 16 + q) * 32 + g * 8];
#pragma unroll
    for (int n = 0; n < 4; n++)
      bfr[n] = *(const short8*)&Bs[(wn * 64 + n * 16 + q) * 32 + g * 8];
#pragma unroll
    for (int m = 0; m < 4; m++)
#pragma unroll
      for (int n = 0; n < 4; n++)
        acc[m][n] = __builtin_amdgcn_mfma_f32_16x16x32_bf16(af[m], bfr[n], acc[m][n], 0, 0, 0);
    __syncthreads();
  }

#pragma unroll
  for (int n = 0; n < 4; n++) {
    int colg = n0 + wn * 64 + n * 16 + q;
    float bv = bias ? bias[colg] : 0.f;
#pragma unroll
    for (int m = 0; m < 4; m++) {
      int rowb = m0 + wm * 64 + m * 16 + g * 4;
#pragma unroll
      for (int r = 0; r < 4; r++) {
        float val = acc[m][n][r] * scale + bv;
        if (causal == 1 && colg > rowb + r) val = -1e30f;
        if (OUTBF) {
          ((unsigned short*)Cv)[(size_t)z * scz + (size_t)(rowb + r) * ldc + colg] = f2bf(val);
        } else {
          ((float*)Cv)[(size_t)z * scz + (size_t)(rowb + r) * ldc + colg] = val;
        }
      }
    }
  }
}

extern "C" void kernel_launch(void* const* d_in, const int* in_sizes, int n_in,
                              void* d_out, int out_size, void* d_ws, size_t ws_size,
                              hipStream_t stream) {
  const float* x  = (const float*)d_in[0];
  const float* Wa = (const float*)d_in[1];
  const float* ba = (const float*)d_in[2];
  const float* Wp = (const float*)d_in[3];
  const float* bp = (const float*)d_in[4];
  float* out = (float*)d_out;

  char* ws = (char*)d_ws;
  // layout (bytes); vt overlays xb (xb dead after GEMM1). total = 120 MiB
  unsigned short* qkv = (unsigned short*)(ws);                 // 50331648
  unsigned short* xb  = (unsigned short*)(ws + 50331648);      // 16777216
  unsigned short* vt  = (unsigned short*)(ws + 50331648);      // overlay xb
  unsigned short* wta = (unsigned short*)(ws + 67108864);      // 6291456
  unsigned short* S   = (unsigned short*)(ws + 73400320);      // 33554432
  unsigned short* y   = (unsigned short*)(ws + 106954752);     // 16777216
  unsigned short* wtp = (unsigned short*)(ws + 123731968);     // 2097152

  conv_x_kernel<<<8192, 256, 0, stream>>>(x, xb);
  transpose_w_kernel<<<dim3(96, 32), dim3(32, 8), 0, stream>>>(Wa, wta, 1024, 3072);
  transpose_w_kernel<<<dim3(32, 32), dim3(32, 8), 0, stream>>>(Wp, wtp, 1024, 1024);

  // qkv = x @ W_attn + b_attn   [8192 x 3072]
  gemm_bt_kernel<1><<<dim3(24, 64, 1), 256, 0, stream>>>(
      xb, 1024, 0, wta, 1024, 0, qkv, 3072, 0, ba, 1024, 1.0f, 0);

  // S = Q @ K^T * 0.125 (causal masked), per batch [2048 x 2048]
  gemm_bt_kernel<1><<<dim3(16, 16, 4), 256, 0, stream>>>(
      qkv, 3072, 2048LL * 3072, qkv + 1024, 3072, 2048LL * 3072,
      S, 2048, 2048LL * 2048, nullptr, 1024, 0.125f, 1);

  softmax_kernel<<<2048, 256, 0, stream>>>(S);

  transpose_v_kernel<<<dim3(64, 32, 4), dim3(32, 8), 0, stream>>>(qkv, vt);

  // y = P @ V, per batch [2048 x 1024], K truncated by causality
  gemm_bt_kernel<1><<<dim3(8, 16, 4), 256, 0, stream>>>(
      S, 2048, 2048LL * 2048, vt, 2048, 1024LL * 2048,
      y, 1024, 2048LL * 1024, nullptr, 2048, 1.0f, 2);

  // out = y @ W_proj + b_proj   [8192 x 1024], fp32 out
  gemm_bt_kernel<0><<<dim3(8, 64, 1), 256, 0, stream>>>(
      y, 1024, 0, wtp, 1024, 0, out, 1024, 0, bp, 1024, 1.0f, 0);
}

// Round 2
// 244.165 us; speedup vs baseline: 1.0837x; 1.0837x over previous
//
#include <hip/hip_runtime.h>

typedef __attribute__((ext_vector_type(8))) short short8;
typedef __attribute__((ext_vector_type(4))) float f32x4;
typedef __attribute__((ext_vector_type(4))) unsigned short ushort4v;

__device__ __forceinline__ unsigned short f2bf(float f) {
  unsigned int u = __float_as_uint(f);
  u += 0x7fffu + ((u >> 16) & 1u);
  return (unsigned short)(u >> 16);
}
__device__ __forceinline__ float bf2f(unsigned short h) {
  return __uint_as_float(((unsigned int)h) << 16);
}

__device__ __forceinline__ void gload16(const unsigned short* g, unsigned short* l) {
  __builtin_amdgcn_global_load_lds(
      (const __attribute__((address_space(1))) unsigned int*)g,
      (__attribute__((address_space(3))) unsigned int*)l,
      16, 0, 0);
}

__device__ __forceinline__ void bar() {
  asm volatile("" ::: "memory");
  __builtin_amdgcn_s_barrier();
  asm volatile("" ::: "memory");
}

// ---------------- convert x (f32) -> bf16 ----------------
__global__ __launch_bounds__(256) void conv_x_kernel(const float* __restrict__ x,
                                                     unsigned short* __restrict__ xb) {
  int i = blockIdx.x * 256 + threadIdx.x;
  f32x4 v = ((const f32x4*)x)[i];
  ushort4v o;
  o[0] = f2bf(v[0]); o[1] = f2bf(v[1]); o[2] = f2bf(v[2]); o[3] = f2bf(v[3]);
  ((ushort4v*)xb)[i] = o;
}

// ------------- transpose+convert W: f32 [K][N] -> bf16 [N][K] -------------
__global__ __launch_bounds__(256) void transpose_w_kernel(const float* __restrict__ W,
                                                          unsigned short* __restrict__ Wt,
                                                          int K, int N) {
  __shared__ float tile[32][33];
  int n0 = blockIdx.x * 32, k0 = blockIdx.y * 32;
  int tx = threadIdx.x, ty = threadIdx.y;
#pragma unroll
  for (int j = 0; j < 32; j += 8)
    tile[ty + j][tx] = W[(size_t)(k0 + ty + j) * N + n0 + tx];
  __syncthreads();
#pragma unroll
  for (int j = 0; j < 32; j += 8)
    Wt[(size_t)(n0 + ty + j) * K + k0 + tx] = f2bf(tile[tx][ty + j]);
}

// ------- transpose V (bf16 part of qkv) -> vt [B][1024][2048] -------
__global__ __launch_bounds__(256) void transpose_v_kernel(const unsigned short* __restrict__ qkv,
                                                          unsigned short* __restrict__ vt) {
  __shared__ unsigned short tile[32][33];
  int b = blockIdx.z;
  int key0 = blockIdx.x * 32, d0 = blockIdx.y * 32;
  int tx = threadIdx.x, ty = threadIdx.y;
#pragma unroll
  for (int j = 0; j < 32; j += 8)
    tile[ty + j][tx] = qkv[(size_t)(b * 2048 + key0 + ty + j) * 3072 + 2048 + d0 + tx];
  __syncthreads();
#pragma unroll
  for (int j = 0; j < 32; j += 8)
    vt[(size_t)(b * 1024 + d0 + ty + j) * 2048 + key0 + tx] = tile[tx][ty + j];
}

// ---------------- row softmax on S (bf16, in place), rows of 2048 ---------
__global__ __launch_bounds__(256) void softmax_kernel(unsigned short* __restrict__ S) {
  int row = blockIdx.x * 4 + (threadIdx.x >> 6);
  int l = threadIdx.x & 63;
  unsigned short* p = S + (size_t)row * 2048;
  float v[32];
#pragma unroll
  for (int i = 0; i < 4; i++) {
    short8 raw = *(const short8*)&p[(i * 64 + l) * 8];
#pragma unroll
    for (int j = 0; j < 8; j++) v[i * 8 + j] = bf2f((unsigned short)raw[j]);
  }
  float mx = -3e38f;
#pragma unroll
  for (int i = 0; i < 32; i++) mx = fmaxf(mx, v[i]);
#pragma unroll
  for (int off = 1; off < 64; off <<= 1) mx = fmaxf(mx, __shfl_xor(mx, off));
  float s = 0.f;
#pragma unroll
  for (int i = 0; i < 32; i++) { v[i] = exp2f((v[i] - mx) * 1.44269504f); s += v[i]; }
#pragma unroll
  for (int off = 1; off < 64; off <<= 1) s += __shfl_xor(s, off);
  float inv = 1.f / s;
#pragma unroll
  for (int i = 0; i < 4; i++) {
    short8 o;
#pragma unroll
    for (int j = 0; j < 8; j++) o[j] = (short)f2bf(v[i * 8 + j] * inv);
    *(short8*)&p[(i * 64 + l) * 8] = o;
  }
}

// ============ 256x256 8-phase GEMM: C = A[M][K] @ Bt[N][K]^T * scale + bias
// 512 threads = 8 waves (2 M x 4 N); BK=64; LDS 128 KiB double-buffered.
// LDS swizzle: colShort ^= (row&7)<<3 on read; staging sources pre-swizzled.
template <int OUTBF>
__global__ __launch_bounds__(512) void gemm256_kernel(
    const unsigned short* __restrict__ A, int lda, long long saz,
    const unsigned short* __restrict__ Bt, int ldb, long long sbz,
    void* __restrict__ Cv, int ldc, long long scz,
    const float* __restrict__ bias, int K, float scale, int causal) {
  __shared__ unsigned short Alds[2][16384];  // [db][256 rows][64 cols]
  __shared__ unsigned short Blds[2][16384];

  const int m0 = blockIdx.y * 256, n0 = blockIdx.x * 256;
  const int z = blockIdx.z;
  A += (size_t)z * saz;
  Bt += (size_t)z * sbz;

  const int t = threadIdx.x;
  const int lane = t & 63, wid = t >> 6;
  const int g = lane >> 4, q = lane & 15;
  const int wm = wid >> 2, wn = wid & 3;  // wave tile: rows wm*128, cols wn*64

  int NT = K >> 6;
  if (causal == 1) { if (n0 >= m0 + 256) NT = 0; }
  else if (causal == 2) { NT = min(K, m0 + 256) >> 6; }

  f32x4 acc[8][4] = {};

  if (NT > 0) {
    // staging: thread t covers LDS bytes [t*16, t*16+16) of an 8KB chunk
    const int srow = t >> 3;                              // 0..63
    const int scol = ((t & 7) * 8) ^ ((srow & 7) << 3);   // inverse-swizzled col
    const unsigned short* aSB = A + (size_t)(m0 + srow) * lda + scol;
    const unsigned short* bSB = Bt + (size_t)(n0 + srow) * ldb + scol;

    auto stA = [&](int tile, int h) {
      unsigned short* d = &Alds[tile & 1][h * 8192 + wid * 512];
      const unsigned short* s = aSB + (size_t)(h * 128) * lda + tile * 64;
      gload16(s, d);
      gload16(s + (size_t)64 * lda, d + 4096);
    };
    auto stB = [&](int tile, int h) {
      unsigned short* d = &Blds[tile & 1][h * 8192 + wid * 512];
      const unsigned short* s = bSB + (size_t)(h * 128) * ldb + tile * 64;
      gload16(s, d);
      gload16(s + (size_t)64 * ldb, d + 4096);
    };

    // fragment read bases (shorts); swizzle on col bits 3-5
    const int lcol = (g * 8) ^ ((q & 7) << 3);
    const int laneA = wm * 8192 + q * 64 + lcol;
    const int laneB = wn * 4096 + q * 64 + lcol;
    auto ldA = [&](int db, int m, int ks) {
      return *(const short8*)&Alds[db][(laneA + m * 1024) ^ (ks * 32)];
    };
    auto ldB = [&](int db, int n, int ks) {
      return *(const short8*)&Blds[db][(laneB + n * 1024) ^ (ks * 32)];
    };

    // prologue: tile0 fully, tile1 first 3 halves
    stB(0, 0); stB(0, 1); stA(0, 0); stA(0, 1);
    if (NT > 1) {
      stB(1, 0); stB(1, 1); stA(1, 0);
      asm volatile("s_waitcnt vmcnt(6)" ::: "memory");
    } else {
      asm volatile("s_waitcnt vmcnt(0)" ::: "memory");
    }
    bar();

    for (int tt = 0; tt < NT; ++tt) {
      const int db = tt & 1;
      short8 aq[4][2], bq[4][2];
      // ---- phase 1: read A m0-3 + B n0-1; stage (tt+1).A-half1 ----
#pragma unroll
      for (int m = 0; m < 4; m++) { aq[m][0] = ldA(db, m, 0); aq[m][1] = ldA(db, m, 1); }
#pragma unroll
      for (int n = 0; n < 2; n++) { bq[n][0] = ldB(db, n, 0); bq[n][1] = ldB(db, n, 1); }
      if (tt + 1 < NT) stA(tt + 1, 1);
      bar();
      asm volatile("s_waitcnt lgkmcnt(0)" ::: "memory");
      __builtin_amdgcn_sched_barrier(0);
      __builtin_amdgcn_s_setprio(1);
#pragma unroll
      for (int m = 0; m < 4; m++)
#pragma unroll
        for (int n = 0; n < 2; n++) {
          acc[m][n] = __builtin_amdgcn_mfma_f32_16x16x32_bf16(aq[m][0], bq[n][0], acc[m][n], 0, 0, 0);
          acc[m][n] = __builtin_amdgcn_mfma_f32_16x16x32_bf16(aq[m][1], bq[n][1], acc[m][n], 0, 0, 0);
        }
      __builtin_amdgcn_sched_barrier(0);
      __builtin_amdgcn_s_setprio(0);
      bar();
      // ---- phase 2: read B n2-3; stage (tt+2).B-half0 ----
#pragma unroll
      for (int n = 2; n < 4; n++) { bq[n][0] = ldB(db, n, 0); bq[n][1] = ldB(db, n, 1); }
      if (tt + 2 < NT) stB(tt + 2, 0);
      bar();
      asm volatile("s_waitcnt lgkmcnt(0)" ::: "memory");
      __builtin_amdgcn_sched_barrier(0);
      __builtin_amdgcn_s_setprio(1);
#pragma unroll
      for (int m = 0; m < 4; m++)
#pragma unroll
        for (int n = 2; n < 4; n++) {
          acc[m][n] = __builtin_amdgcn_mfma_f32_16x16x32_bf16(aq[m][0], bq[n][0], acc[m][n], 0, 0, 0);
          acc[m][n] = __builtin_amdgcn_mfma_f32_16x16x32_bf16(aq[m][1], bq[n][1], acc[m][n], 0, 0, 0);
        }
      __builtin_amdgcn_sched_barrier(0);
      __builtin_amdgcn_s_setprio(0);
      bar();
      // ---- phase 3: read A m4-7; stage (tt+2).B-half1 ----
#pragma unroll
      for (int m = 0; m < 4; m++) { aq[m][0] = ldA(db, m + 4, 0); aq[m][1] = ldA(db, m + 4, 1); }
      if (tt + 2 < NT) stB(tt + 2, 1);
      bar();
      asm volatile("s_waitcnt lgkmcnt(0)" ::: "memory");
      __builtin_amdgcn_sched_barrier(0);
      __builtin_amdgcn_s_setprio(1);
#pragma unroll
      for (int m = 0; m < 4; m++)
#pragma unroll
        for (int n = 0; n < 2; n++) {
          acc[m + 4][n] = __builtin_amdgcn_mfma_f32_16x16x32_bf16(aq[m][0], bq[n][0], acc[m + 4][n], 0, 0, 0);
          acc[m + 4][n] = __builtin_amdgcn_mfma_f32_16x16x32_bf16(aq[m][1], bq[n][1], acc[m + 4][n], 0, 0, 0);
        }
      __builtin_amdgcn_sched_barrier(0);
      __builtin_amdgcn_s_setprio(0);
      bar();
      // ---- phase 4: stage (tt+2).A-half0; counted vmcnt ----
      if (tt + 2 < NT) {
        stA(tt + 2, 0);
        asm volatile("s_waitcnt vmcnt(6)" ::: "memory");
      } else {
        asm volatile("s_waitcnt vmcnt(0)" ::: "memory");
      }
      bar();
      __builtin_amdgcn_sched_barrier(0);
      __builtin_amdgcn_s_setprio(1);
#pragma unroll
      for (int m = 0; m < 4; m++)
#pragma unroll
        for (int n = 2; n < 4; n++) {
          acc[m + 4][n] = __builtin_amdgcn_mfma_f32_16x16x32_bf16(aq[m][0], bq[n][0], acc[m + 4][n], 0, 0, 0);
          acc[m + 4][n] = __builtin_amdgcn_mfma_f32_16x16x32_bf16(aq[m][1], bq[n][1], acc[m + 4][n], 0, 0, 0);
        }
      __builtin_amdgcn_sched_barrier(0);
      __builtin_amdgcn_s_setprio(0);
      bar();
    }
  }

  // ---- epilogue ----
#pragma unroll
  for (int n = 0; n < 4; n++) {
    int colg = n0 + wn * 64 + n * 16 + q;
    float bv = bias ? bias[colg] : 0.f;
#pragma unroll
    for (int m = 0; m < 8; m++) {
      int rowb = m0 + wm * 128 + m * 16 + g * 4;
#pragma unroll
      for (int r = 0; r < 4; r++) {
        float val = acc[m][n][r] * scale + bv;
        if (causal == 1 && colg > rowb + r) val = -1e30f;
        if (OUTBF) {
          ((unsigned short*)Cv)[(size_t)z * scz + (size_t)(rowb + r) * ldc + colg] = f2bf(val);
        } else {
          ((float*)Cv)[(size_t)z * scz + (size_t)(rowb + r) * ldc + colg] = val;
        }
      }
    }
  }
}

extern "C" void kernel_launch(void* const* d_in, const int* in_sizes, int n_in,
                              void* d_out, int out_size, void* d_ws, size_t ws_size,
                              hipStream_t stream) {
  const float* x  = (const float*)d_in[0];
  const float* Wa = (const float*)d_in[1];
  const float* ba = (const float*)d_in[2];
  const float* Wp = (const float*)d_in[3];
  const float* bp = (const float*)d_in[4];
  float* out = (float*)d_out;

  char* ws = (char*)d_ws;
  unsigned short* qkv = (unsigned short*)(ws);                 // 50331648
  unsigned short* xb  = (unsigned short*)(ws + 50331648);      // 16777216
  unsigned short* vt  = (unsigned short*)(ws + 50331648);      // overlay xb
  unsigned short* wta = (unsigned short*)(ws + 67108864);      // 6291456
  unsigned short* S   = (unsigned short*)(ws + 73400320);      // 33554432
  unsigned short* y   = (unsigned short*)(ws + 106954752);     // 16777216
  unsigned short* wtp = (unsigned short*)(ws + 123731968);     // 2097152

  conv_x_kernel<<<8192, 256, 0, stream>>>(x, xb);
  transpose_w_kernel<<<dim3(96, 32), dim3(32, 8), 0, stream>>>(Wa, wta, 1024, 3072);
  transpose_w_kernel<<<dim3(32, 32), dim3(32, 8), 0, stream>>>(Wp, wtp, 1024, 1024);

  // qkv = x @ W_attn + b_attn   [8192 x 3072]
  gemm256_kernel<1><<<dim3(12, 32, 1), 512, 0, stream>>>(
      xb, 1024, 0, wta, 1024, 0, qkv, 3072, 0, ba, 1024, 1.0f, 0);

  // S = Q @ K^T * 0.125 (causal masked), per batch [2048 x 2048]
  gemm256_kernel<1><<<dim3(8, 8, 4), 512, 0, stream>>>(
      qkv, 3072, 2048LL * 3072, qkv + 1024, 3072, 2048LL * 3072,
      S, 2048, 2048LL * 2048, nullptr, 1024, 0.125f, 1);

  softmax_kernel<<<2048, 256, 0, stream>>>(S);

  transpose_v_kernel<<<dim3(64, 32, 4), dim3(32, 8), 0, stream>>>(qkv, vt);

  // y = P @ V, per batch [2048 x 1024], K truncated by causality
  gemm256_kernel<1><<<dim3(4, 8, 4), 512, 0, stream>>>(
      S, 2048, 2048LL * 2048, vt, 2048, 1024LL * 2048,
      y, 1024, 2048LL * 1024, nullptr, 2048, 1.0f, 2);

  // out = y @ W_proj + b_proj   [8192 x 1024], fp32 out
  gemm256_kernel<0><<<dim3(4, 32, 1), 512, 0, stream>>>(
      y, 1024, 0, wtp, 1024, 0, out, 1024, 0, bp, 1024, 1.0f, 0);
}

// Round 3
// 238.639 us; speedup vs baseline: 1.1088x; 1.0232x over previous
//
#include <hip/hip_runtime.h>

typedef __attribute__((ext_vector_type(8))) short short8;
typedef __attribute__((ext_vector_type(4))) float f32x4;
typedef __attribute__((ext_vector_type(4))) unsigned short ushort4v;

struct DB0 { static constexpr int value = 0; };
struct DB1 { static constexpr int value = 1; };

__device__ __forceinline__ unsigned short f2bf(float f) {
  unsigned int u = __float_as_uint(f);
  u += 0x7fffu + ((u >> 16) & 1u);
  return (unsigned short)(u >> 16);
}
__device__ __forceinline__ float bf2f(unsigned short h) {
  return __uint_as_float(((unsigned int)h) << 16);
}

__device__ __forceinline__ void gload16(const unsigned short* g, unsigned short* l) {
  __builtin_amdgcn_global_load_lds(
      (const __attribute__((address_space(1))) unsigned int*)g,
      (__attribute__((address_space(3))) unsigned int*)l,
      16, 0, 0);
}

// inline-asm ds_read_b128: invisible to compiler alias tracking, so no
// auto-inserted vmcnt(0) ordering vs in-flight global_load_lds DMAs.
template <int OFF>
__device__ __forceinline__ short8 dsr(unsigned a) {
  short8 r;
  asm volatile("ds_read_b128 %0, %1 offset:%2" : "=v"(r) : "v"(a), "n"(OFF));
  return r;
}

__device__ __forceinline__ void bar() {
  asm volatile("" ::: "memory");
  __builtin_amdgcn_s_barrier();
  asm volatile("" ::: "memory");
}

// ---------------- convert x (f32) -> bf16 ----------------
__global__ __launch_bounds__(256) void conv_x_kernel(const float* __restrict__ x,
                                                     unsigned short* __restrict__ xb) {
  int i = blockIdx.x * 256 + threadIdx.x;
  f32x4 v = ((const f32x4*)x)[i];
  ushort4v o;
  o[0] = f2bf(v[0]); o[1] = f2bf(v[1]); o[2] = f2bf(v[2]); o[3] = f2bf(v[3]);
  ((ushort4v*)xb)[i] = o;
}

// ------------- transpose+convert W: f32 [K][N] -> bf16 [N][K] -------------
__global__ __launch_bounds__(256) void transpose_w_kernel(const float* __restrict__ W,
                                                          unsigned short* __restrict__ Wt,
                                                          int K, int N) {
  __shared__ float tile[32][33];
  int n0 = blockIdx.x * 32, k0 = blockIdx.y * 32;
  int tx = threadIdx.x, ty = threadIdx.y;
#pragma unroll
  for (int j = 0; j < 32; j += 8)
    tile[ty + j][tx] = W[(size_t)(k0 + ty + j) * N + n0 + tx];
  __syncthreads();
#pragma unroll
  for (int j = 0; j < 32; j += 8)
    Wt[(size_t)(n0 + ty + j) * K + k0 + tx] = f2bf(tile[tx][ty + j]);
}

// ------- transpose V (bf16 part of qkv) -> vt [B][1024][2048] -------
__global__ __launch_bounds__(256) void transpose_v_kernel(const unsigned short* __restrict__ qkv,
                                                          unsigned short* __restrict__ vt) {
  __shared__ unsigned short tile[32][33];
  int b = blockIdx.z;
  int key0 = blockIdx.x * 32, d0 = blockIdx.y * 32;
  int tx = threadIdx.x, ty = threadIdx.y;
#pragma unroll
  for (int j = 0; j < 32; j += 8)
    tile[ty + j][tx] = qkv[(size_t)(b * 2048 + key0 + ty + j) * 3072 + 2048 + d0 + tx];
  __syncthreads();
#pragma unroll
  for (int j = 0; j < 32; j += 8)
    vt[(size_t)(b * 1024 + d0 + ty + j) * 2048 + key0 + tx] = tile[tx][ty + j];
}

// ---------------- row softmax on S (bf16, in place), rows of 2048 ---------
__global__ __launch_bounds__(256) void softmax_kernel(unsigned short* __restrict__ S) {
  int row = blockIdx.x * 4 + (threadIdx.x >> 6);
  int l = threadIdx.x & 63;
  unsigned short* p = S + (size_t)row * 2048;
  float v[32];
#pragma unroll
  for (int i = 0; i < 4; i++) {
    short8 raw = *(const short8*)&p[(i * 64 + l) * 8];
#pragma unroll
    for (int j = 0; j < 8; j++) v[i * 8 + j] = bf2f((unsigned short)raw[j]);
  }
  float mx = -3e38f;
#pragma unroll
  for (int i = 0; i < 32; i++) mx = fmaxf(mx, v[i]);
#pragma unroll
  for (int off = 1; off < 64; off <<= 1) mx = fmaxf(mx, __shfl_xor(mx, off));
  float s = 0.f;
#pragma unroll
  for (int i = 0; i < 32; i++) { v[i] = exp2f((v[i] - mx) * 1.44269504f); s += v[i]; }
#pragma unroll
  for (int off = 1; off < 64; off <<= 1) s += __shfl_xor(s, off);
  float inv = 1.f / s;
#pragma unroll
  for (int i = 0; i < 4; i++) {
    short8 o;
#pragma unroll
    for (int j = 0; j < 8; j++) o[j] = (short)f2bf(v[i * 8 + j] * inv);
    *(short8*)&p[(i * 64 + l) * 8] = o;
  }
}

// ============ 256x256 8-phase GEMM: C = A[M][K] @ Bt[N][K]^T * scale + bias
// 512 threads = 8 waves (2M x 4N); BK=64; LDS 128 KiB double-buffered.
// lds[0..1] = A db0/db1, lds[2..3] = B db0/db1. XOR swizzle on col bits.
template <int OUTBF>
__global__ __launch_bounds__(512) void gemm256_kernel(
    const unsigned short* __restrict__ A, int lda, long long saz,
    const unsigned short* __restrict__ Bt, int ldb, long long sbz,
    void* __restrict__ Cv, int ldc, long long scz,
    const float* __restrict__ bias, int K, float scale, int causal) {
  __shared__ __align__(16) unsigned short lds[4][16384];

  // bijective XCD swizzle over the (x,y) grid (all our grids have nwg%8==0)
  int bx = blockIdx.x, by = blockIdx.y;
  {
    int gx = gridDim.x, gy = gridDim.y;
    int n = gx * gy;
    if ((n & 7) == 0) {
      int id = by * gx + bx;
      id = (id & 7) * (n >> 3) + (id >> 3);
      bx = id % gx;
      by = id / gx;
    }
  }
  const int m0 = by * 256, n0 = bx * 256;
  const int z = blockIdx.z;
  A += (size_t)z * saz;
  Bt += (size_t)z * sbz;

  const int t = threadIdx.x;
  const int lane = t & 63, wid = t >> 6;
  const int g = lane >> 4, q = lane & 15;
  const int wm = wid >> 2, wn = wid & 3;  // wave tile: rows wm*128, cols wn*64

  int NT = K >> 6;
  if (causal == 1) { if (n0 >= m0 + 256) NT = 0; }
  else if (causal == 2) { NT = min(K, m0 + 256) >> 6; }

  f32x4 acc[8][4] = {};

  if (NT > 0) {
    // ---- staging (global -> LDS, pre-swizzled source) ----
    const int srow = t >> 3;
    const int scol = ((t & 7) * 8) ^ ((srow & 7) << 3);
    const unsigned short* aSB = A + (size_t)(m0 + srow) * lda + scol;
    const unsigned short* bSB = Bt + (size_t)(n0 + srow) * ldb + scol;

    auto stA = [&](int db, int tile, int h) {
      unsigned short* d = (unsigned short*)&lds[db][h * 8192 + wid * 512];
      const unsigned short* s = aSB + (size_t)(h * 128) * lda + tile * 64;
      gload16(s, d);
      gload16(s + (size_t)64 * lda, d + 4096);
    };
    auto stB = [&](int db, int tile, int h) {
      unsigned short* d = (unsigned short*)&lds[2 + db][h * 8192 + wid * 512];
      const unsigned short* s = bSB + (size_t)(h * 128) * ldb + tile * 64;
      gload16(s, d);
      gload16(s + (size_t)64 * ldb, d + 4096);
    };

    // ---- fragment read addresses (LDS byte offsets) ----
    const unsigned base =
        (unsigned)(unsigned long long)(__attribute__((address_space(3))) unsigned short*)&lds[0][0];
    const int lcol = (g * 8) ^ ((q & 7) << 3);
    const unsigned aAk0 = base + (unsigned)(wm * 8192 + q * 64 + lcol) * 2u;
    const unsigned aAk1 = base + (unsigned)(wm * 8192 + q * 64 + (lcol ^ 32)) * 2u;
    const unsigned bBk0 = base + 65536u + (unsigned)(wn * 4096 + q * 64 + lcol) * 2u;
    const unsigned bBk1 = base + 65536u + (unsigned)(wn * 4096 + q * 64 + (lcol ^ 32)) * 2u;

    // prologue: tile0 fully, tile1 first 3 halves
    stB(0, 0, 0); stB(0, 0, 1); stA(0, 0, 0); stA(0, 0, 1);
    if (NT > 1) {
      stB(1, 1, 0); stB(1, 1, 1); stA(1, 1, 0);
      asm volatile("s_waitcnt vmcnt(6)" ::: "memory");
    } else {
      asm volatile("s_waitcnt vmcnt(0)" ::: "memory");
    }
    bar();

    auto body = [&](auto dbc, int tt) {
      constexpr int DB = decltype(dbc)::value;
      const unsigned aa0 = aAk0 + DB * 32768u, aa1 = aAk1 + DB * 32768u;
      const unsigned bb0 = bBk0 + DB * 32768u, bb1 = bBk1 + DB * 32768u;
      short8 aq[4][2], bq[4][2];
      // ---- phase 1: read A m0-3 + B n0-1; stage (tt+1).A-half1 ----
      aq[0][0] = dsr<0>(aa0);    aq[0][1] = dsr<0>(aa1);
      aq[1][0] = dsr<2048>(aa0); aq[1][1] = dsr<2048>(aa1);
      aq[2][0] = dsr<4096>(aa0); aq[2][1] = dsr<4096>(aa1);
      aq[3][0] = dsr<6144>(aa0); aq[3][1] = dsr<6144>(aa1);
      bq[0][0] = dsr<0>(bb0);    bq[0][1] = dsr<0>(bb1);
      bq[1][0] = dsr<2048>(bb0); bq[1][1] = dsr<2048>(bb1);
      if (tt + 1 < NT) stA(DB ^ 1, tt + 1, 1);
      bar();
      asm volatile("s_waitcnt lgkmcnt(0)" ::: "memory");
      __builtin_amdgcn_sched_barrier(0);
      __builtin_amdgcn_s_setprio(1);
#pragma unroll
      for (int m = 0; m < 4; m++)
#pragma unroll
        for (int n = 0; n < 2; n++) {
          acc[m][n] = __builtin_amdgcn_mfma_f32_16x16x32_bf16(aq[m][0], bq[n][0], acc[m][n], 0, 0, 0);
          acc[m][n] = __builtin_amdgcn_mfma_f32_16x16x32_bf16(aq[m][1], bq[n][1], acc[m][n], 0, 0, 0);
        }
      __builtin_amdgcn_sched_barrier(0);
      __builtin_amdgcn_s_setprio(0);
      bar();
      // ---- phase 2: read B n2-3; stage (tt+2).B-half0 ----
      bq[2][0] = dsr<4096>(bb0); bq[2][1] = dsr<4096>(bb1);
      bq[3][0] = dsr<6144>(bb0); bq[3][1] = dsr<6144>(bb1);
      if (tt + 2 < NT) stB(DB, tt + 2, 0);
      bar();
      asm volatile("s_waitcnt lgkmcnt(0)" ::: "memory");
      __builtin_amdgcn_sched_barrier(0);
      __builtin_amdgcn_s_setprio(1);
#pragma unroll
      for (int m = 0; m < 4; m++)
#pragma unroll
        for (int n = 2; n < 4; n++) {
          acc[m][n] = __builtin_amdgcn_mfma_f32_16x16x32_bf16(aq[m][0], bq[n][0], acc[m][n], 0, 0, 0);
          acc[m][n] = __builtin_amdgcn_mfma_f32_16x16x32_bf16(aq[m][1], bq[n][1], acc[m][n], 0, 0, 0);
        }
      __builtin_amdgcn_sched_barrier(0);
      __builtin_amdgcn_s_setprio(0);
      bar();
      // ---- phase 3: read A m4-7; stage (tt+2).B-half1 ----
      aq[0][0] = dsr<8192>(aa0);  aq[0][1] = dsr<8192>(aa1);
      aq[1][0] = dsr<10240>(aa0); aq[1][1] = dsr<10240>(aa1);
      aq[2][0] = dsr<12288>(aa0); aq[2][1] = dsr<12288>(aa1);
      aq[3][0] = dsr<14336>(aa0); aq[3][1] = dsr<14336>(aa1);
      if (tt + 2 < NT) stB(DB, tt + 2, 1);
      bar();
      asm volatile("s_waitcnt lgkmcnt(0)" ::: "memory");
      __builtin_amdgcn_sched_barrier(0);
      __builtin_amdgcn_s_setprio(1);
#pragma unroll
      for (int m = 0; m < 4; m++)
#pragma unroll
        for (int n = 0; n < 2; n++) {
          acc[m + 4][n] = __builtin_amdgcn_mfma_f32_16x16x32_bf16(aq[m][0], bq[n][0], acc[m + 4][n], 0, 0, 0);
          acc[m + 4][n] = __builtin_amdgcn_mfma_f32_16x16x32_bf16(aq[m][1], bq[n][1], acc[m + 4][n], 0, 0, 0);
        }
      __builtin_amdgcn_sched_barrier(0);
      __builtin_amdgcn_s_setprio(0);
      bar();
      // ---- phase 4: stage (tt+2).A-half0; counted vmcnt ----
      if (tt + 2 < NT) {
        stA(DB, tt + 2, 0);
        asm volatile("s_waitcnt vmcnt(6)" ::: "memory");
      } else {
        asm volatile("s_waitcnt vmcnt(0)" ::: "memory");
      }
      bar();
      __builtin_amdgcn_sched_barrier(0);
      __builtin_amdgcn_s_setprio(1);
#pragma unroll
      for (int m = 0; m < 4; m++)
#pragma unroll
        for (int n = 2; n < 4; n++) {
          acc[m + 4][n] = __builtin_amdgcn_mfma_f32_16x16x32_bf16(aq[m][0], bq[n][0], acc[m + 4][n], 0, 0, 0);
          acc[m + 4][n] = __builtin_amdgcn_mfma_f32_16x16x32_bf16(aq[m][1], bq[n][1], acc[m + 4][n], 0, 0, 0);
        }
      __builtin_amdgcn_sched_barrier(0);
      __builtin_amdgcn_s_setprio(0);
      bar();
    };

    int tt = 0;
    for (; tt + 2 <= NT; tt += 2) {
      body(DB0{}, tt);
      body(DB1{}, tt + 1);
    }
    if (tt < NT) body(DB0{}, tt);
  }

  // ---- epilogue ----
#pragma unroll
  for (int n = 0; n < 4; n++) {
    int colg = n0 + wn * 64 + n * 16 + q;
    float bv = bias ? bias[colg] : 0.f;
#pragma unroll
    for (int m = 0; m < 8; m++) {
      int rowb = m0 + wm * 128 + m * 16 + g * 4;
#pragma unroll
      for (int r = 0; r < 4; r++) {
        float val = acc[m][n][r] * scale + bv;
        if (causal == 1 && colg > rowb + r) val = -1e30f;
        if (OUTBF) {
          ((unsigned short*)Cv)[(size_t)z * scz + (size_t)(rowb + r) * ldc + colg] = f2bf(val);
        } else {
          ((float*)Cv)[(size_t)z * scz + (size_t)(rowb + r) * ldc + colg] = val;
        }
      }
    }
  }
}

extern "C" void kernel_launch(void* const* d_in, const int* in_sizes, int n_in,
                              void* d_out, int out_size, void* d_ws, size_t ws_size,
                              hipStream_t stream) {
  const float* x  = (const float*)d_in[0];
  const float* Wa = (const float*)d_in[1];
  const float* ba = (const float*)d_in[2];
  const float* Wp = (const float*)d_in[3];
  const float* bp = (const float*)d_in[4];
  float* out = (float*)d_out;

  char* ws = (char*)d_ws;
  unsigned short* qkv = (unsigned short*)(ws);                 // 50331648
  unsigned short* xb  = (unsigned short*)(ws + 50331648);      // 16777216
  unsigned short* vt  = (unsigned short*)(ws + 50331648);      // overlay xb
  unsigned short* wta = (unsigned short*)(ws + 67108864);      // 6291456
  unsigned short* S   = (unsigned short*)(ws + 73400320);      // 33554432
  unsigned short* y   = (unsigned short*)(ws + 106954752);     // 16777216
  unsigned short* wtp = (unsigned short*)(ws + 123731968);     // 2097152

  conv_x_kernel<<<8192, 256, 0, stream>>>(x, xb);
  transpose_w_kernel<<<dim3(96, 32), dim3(32, 8), 0, stream>>>(Wa, wta, 1024, 3072);
  transpose_w_kernel<<<dim3(32, 32), dim3(32, 8), 0, stream>>>(Wp, wtp, 1024, 1024);

  // qkv = x @ W_attn + b_attn   [8192 x 3072]
  gemm256_kernel<1><<<dim3(12, 32, 1), 512, 0, stream>>>(
      xb, 1024, 0, wta, 1024, 0, qkv, 3072, 0, ba, 1024, 1.0f, 0);

  // S = Q @ K^T * 0.125 (causal masked), per batch [2048 x 2048]
  gemm256_kernel<1><<<dim3(8, 8, 4), 512, 0, stream>>>(
      qkv, 3072, 2048LL * 3072, qkv + 1024, 3072, 2048LL * 3072,
      S, 2048, 2048LL * 2048, nullptr, 1024, 0.125f, 1);

  softmax_kernel<<<2048, 256, 0, stream>>>(S);

  transpose_v_kernel<<<dim3(64, 32, 4), dim3(32, 8), 0, stream>>>(qkv, vt);

  // y = P @ V, per batch [2048 x 1024], K truncated by causality
  gemm256_kernel<1><<<dim3(4, 8, 4), 512, 0, stream>>>(
      S, 2048, 2048LL * 2048, vt, 2048, 1024LL * 2048,
      y, 1024, 2048LL * 1024, nullptr, 2048, 1.0f, 2);

  // out = y @ W_proj + b_proj   [8192 x 1024], fp32 out
  gemm256_kernel<0><<<dim3(4, 32, 1), 512, 0, stream>>>(
      y, 1024, 0, wtp, 1024, 0, out, 1024, 0, bp, 1024, 1.0f, 0);
}

// Round 4
// 219.612 us; speedup vs baseline: 1.2048x; 1.0866x over previous
//
#include <hip/hip_runtime.h>

typedef __attribute__((ext_vector_type(8))) short short8;
typedef __attribute__((ext_vector_type(4))) float f32x4;
typedef __attribute__((ext_vector_type(4))) unsigned short ushort4v;

__device__ __forceinline__ unsigned short f2bf(float f) {
  unsigned int u = __float_as_uint(f);
  u += 0x7fffu + ((u >> 16) & 1u);
  return (unsigned short)(u >> 16);
}
__device__ __forceinline__ float bf2f(unsigned short h) {
  return __uint_as_float(((unsigned int)h) << 16);
}

__device__ __forceinline__ void gload16(const unsigned short* g, unsigned short* l) {
  __builtin_amdgcn_global_load_lds(
      (const __attribute__((address_space(1))) unsigned int*)g,
      (__attribute__((address_space(3))) unsigned int*)l,
      16, 0, 0);
}

__device__ __forceinline__ void bar() {
  asm volatile("" ::: "memory");
  __builtin_amdgcn_s_barrier();
  asm volatile("" ::: "memory");
}

// ---------------- convert x (f32) -> bf16 ----------------
__global__ __launch_bounds__(256) void conv_x_kernel(const float* __restrict__ x,
                                                     unsigned short* __restrict__ xb) {
  int i = blockIdx.x * 256 + threadIdx.x;
  f32x4 v = ((const f32x4*)x)[i];
  ushort4v o;
  o[0] = f2bf(v[0]); o[1] = f2bf(v[1]); o[2] = f2bf(v[2]); o[3] = f2bf(v[3]);
  ((ushort4v*)xb)[i] = o;
}

// ------------- transpose+convert W: f32 [K][N] -> bf16 [N][K] -------------
__global__ __launch_bounds__(256) void transpose_w_kernel(const float* __restrict__ W,
                                                          unsigned short* __restrict__ Wt,
                                                          int K, int N) {
  __shared__ float tile[32][33];
  int n0 = blockIdx.x * 32, k0 = blockIdx.y * 32;
  int tx = threadIdx.x, ty = threadIdx.y;
#pragma unroll
  for (int j = 0; j < 32; j += 8)
    tile[ty + j][tx] = W[(size_t)(k0 + ty + j) * N + n0 + tx];
  __syncthreads();
#pragma unroll
  for (int j = 0; j < 32; j += 8)
    Wt[(size_t)(n0 + ty + j) * K + k0 + tx] = f2bf(tile[tx][ty + j]);
}

// ------- transpose V (bf16 part of qkv) -> vt [B][1024][2048] -------
__global__ __launch_bounds__(256) void transpose_v_kernel(const unsigned short* __restrict__ qkv,
                                                          unsigned short* __restrict__ vt) {
  __shared__ unsigned short tile[32][33];
  int b = blockIdx.z;
  int key0 = blockIdx.x * 32, d0 = blockIdx.y * 32;
  int tx = threadIdx.x, ty = threadIdx.y;
#pragma unroll
  for (int j = 0; j < 32; j += 8)
    tile[ty + j][tx] = qkv[(size_t)(b * 2048 + key0 + ty + j) * 3072 + 2048 + d0 + tx];
  __syncthreads();
#pragma unroll
  for (int j = 0; j < 32; j += 8)
    vt[(size_t)(b * 1024 + d0 + ty + j) * 2048 + key0 + tx] = tile[tx][ty + j];
}

// ---------------- row softmax on S (bf16, in place), rows of 2048 ---------
__global__ __launch_bounds__(256) void softmax_kernel(unsigned short* __restrict__ S) {
  int row = blockIdx.x * 4 + (threadIdx.x >> 6);
  int l = threadIdx.x & 63;
  unsigned short* p = S + (size_t)row * 2048;
  float v[32];
#pragma unroll
  for (int i = 0; i < 4; i++) {
    short8 raw = *(const short8*)&p[(i * 64 + l) * 8];
#pragma unroll
    for (int j = 0; j < 8; j++) v[i * 8 + j] = bf2f((unsigned short)raw[j]);
  }
  float mx = -3e38f;
#pragma unroll
  for (int i = 0; i < 32; i++) mx = fmaxf(mx, v[i]);
#pragma unroll
  for (int off = 1; off < 64; off <<= 1) mx = fmaxf(mx, __shfl_xor(mx, off));
  float s = 0.f;
#pragma unroll
  for (int i = 0; i < 32; i++) { v[i] = exp2f((v[i] - mx) * 1.44269504f); s += v[i]; }
#pragma unroll
  for (int off = 1; off < 64; off <<= 1) s += __shfl_xor(s, off);
  float inv = 1.f / s;
#pragma unroll
  for (int i = 0; i < 4; i++) {
    short8 o;
#pragma unroll
    for (int j = 0; j < 8; j++) o[j] = (short)f2bf(v[i * 8 + j] * inv);
    *(short8*)&p[(i * 64 + l) * 8] = o;
  }
}

// ============ 128x128 GEMM, BK=32, 4 waves, 4-deep LDS ring ============
// C[M][N] = A[M][K] @ Bt[N][K]^T * scale + bias.
// Per K-tile: stage tile tt+2 (4x gload16), counted vmcnt(8), ONE barrier,
// then 8x ds_read_b128 + 16x MFMA. LDS 64KB -> 2 blocks/CU; ~full-resident
// grids absorb ragged tails. XOR chunk swizzle (2-way max, free).
template <int OUTBF>
__global__ __launch_bounds__(256) void gemm128_kernel(
    const unsigned short* __restrict__ A, int lda, long long saz,
    const unsigned short* __restrict__ Bt, int ldb, long long sbz,
    void* __restrict__ Cv, int ldc, long long scz,
    const float* __restrict__ bias, int K, float scale, int causal) {
  // per buf (16KB): A = shorts [0,4096) (128 rows x 32), B = [4096,8192)
  __shared__ __align__(16) unsigned short lds[4][8192];

  const int m0 = blockIdx.y * 128, n0 = blockIdx.x * 128;
  const int z = blockIdx.z;
  A += (size_t)z * saz;
  Bt += (size_t)z * sbz;

  const int t = threadIdx.x;
  const int lane = t & 63, wid = t >> 6;
  const int g = lane >> 4, q = lane & 15;
  const int wm = wid >> 1, wn = wid & 1;  // wave tile 64x64

  int NT = K >> 5;
  if (causal == 1) { if (n0 >= m0 + 128) NT = 0; }
  else if (causal == 2) { NT = min(K, m0 + 128) >> 5; }

  f32x4 acc[4][4] = {};

  if (NT > 0) {
    // staging: thread t covers 16B; LDS linear (row = t>>2, chunk = t&3);
    // source column pre-swizzled so read-side XOR recovers logical data
    const int csrc = ((t & 3) ^ ((t >> 2) & 3) ^ ((t >> 4) & 3)) * 8;
    const unsigned short* aS = A + (size_t)(m0 + (t >> 2)) * lda + csrc;
    const unsigned short* bS = Bt + (size_t)(n0 + (t >> 2)) * ldb + csrc;

    auto stage = [&](int tt) {
      unsigned short* d = &lds[tt & 3][wid * 512];
      const unsigned short* sa = aS + tt * 32;
      const unsigned short* sb = bS + tt * 32;
      gload16(sa, d);                           // A rows 0-63
      gload16(sa + (size_t)64 * lda, d + 2048); // A rows 64-127
      gload16(sb, d + 4096);                    // B rows 0-63
      gload16(sb + (size_t)64 * ldb, d + 6144); // B rows 64-127
    };

    // read-side swizzle: chunk = g ^ (row&3) ^ ((row>>2)&3); row%16 == q
    const int chunk = (g ^ (q & 3) ^ ((q >> 2) & 3)) * 8;
    const int aOff = (wm * 64 + q) * 32 + chunk;         // shorts
    const int bOff = 4096 + (wn * 64 + q) * 32 + chunk;  // shorts

    stage(0);
    if (NT > 1) stage(1);

    for (int tt = 0; tt < NT; ++tt) {
      if (tt + 2 < NT) {
        stage(tt + 2);
        asm volatile("s_waitcnt vmcnt(8)" ::: "memory");  // tile tt arrived
      } else if (tt + 1 < NT) {
        asm volatile("s_waitcnt vmcnt(4)" ::: "memory");
      } else {
        asm volatile("s_waitcnt vmcnt(0)" ::: "memory");
      }
      bar();  // all waves' portions of tile tt in LDS

      const unsigned short* buf = lds[tt & 3];
      short8 af[4], bb[4];
#pragma unroll
      for (int m = 0; m < 4; m++) af[m] = *(const short8*)&buf[aOff + m * 512];
#pragma unroll
      for (int n = 0; n < 4; n++) bb[n] = *(const short8*)&buf[bOff + n * 512];
#pragma unroll
      for (int m = 0; m < 4; m++)
#pragma unroll
        for (int n = 0; n < 4; n++)
          acc[m][n] = __builtin_amdgcn_mfma_f32_16x16x32_bf16(af[m], bb[n], acc[m][n], 0, 0, 0);
    }
  }

  // ---- epilogue ----
#pragma unroll
  for (int n = 0; n < 4; n++) {
    int colg = n0 + wn * 64 + n * 16 + q;
    float bv = bias ? bias[colg] : 0.f;
#pragma unroll
    for (int m = 0; m < 4; m++) {
      int rowb = m0 + wm * 64 + m * 16 + g * 4;
#pragma unroll
      for (int r = 0; r < 4; r++) {
        float val = acc[m][n][r] * scale + bv;
        if (causal == 1 && colg > rowb + r) val = -1e30f;
        if (OUTBF) {
          ((unsigned short*)Cv)[(size_t)z * scz + (size_t)(rowb + r) * ldc + colg] = f2bf(val);
        } else {
          ((float*)Cv)[(size_t)z * scz + (size_t)(rowb + r) * ldc + colg] = val;
        }
      }
    }
  }
}

extern "C" void kernel_launch(void* const* d_in, const int* in_sizes, int n_in,
                              void* d_out, int out_size, void* d_ws, size_t ws_size,
                              hipStream_t stream) {
  const float* x  = (const float*)d_in[0];
  const float* Wa = (const float*)d_in[1];
  const float* ba = (const float*)d_in[2];
  const float* Wp = (const float*)d_in[3];
  const float* bp = (const float*)d_in[4];
  float* out = (float*)d_out;

  char* ws = (char*)d_ws;
  unsigned short* qkv = (unsigned short*)(ws);                 // 50331648
  unsigned short* xb  = (unsigned short*)(ws + 50331648);      // 16777216
  unsigned short* vt  = (unsigned short*)(ws + 50331648);      // overlay xb
  unsigned short* wta = (unsigned short*)(ws + 67108864);      // 6291456
  unsigned short* S   = (unsigned short*)(ws + 73400320);      // 33554432
  unsigned short* y   = (unsigned short*)(ws + 106954752);     // 16777216
  unsigned short* wtp = (unsigned short*)(ws + 123731968);     // 2097152

  conv_x_kernel<<<8192, 256, 0, stream>>>(x, xb);
  transpose_w_kernel<<<dim3(96, 32), dim3(32, 8), 0, stream>>>(Wa, wta, 1024, 3072);
  transpose_w_kernel<<<dim3(32, 32), dim3(32, 8), 0, stream>>>(Wp, wtp, 1024, 1024);

  // qkv = x @ W_attn + b_attn   [8192 x 3072]
  gemm128_kernel<1><<<dim3(24, 64, 1), 256, 0, stream>>>(
      xb, 1024, 0, wta, 1024, 0, qkv, 3072, 0, ba, 1024, 1.0f, 0);

  // S = Q @ K^T * 0.125 (causal masked), per batch [2048 x 2048]
  gemm128_kernel<1><<<dim3(16, 16, 4), 256, 0, stream>>>(
      qkv, 3072, 2048LL * 3072, qkv + 1024, 3072, 2048LL * 3072,
      S, 2048, 2048LL * 2048, nullptr, 1024, 0.125f, 1);

  softmax_kernel<<<2048, 256, 0, stream>>>(S);

  transpose_v_kernel<<<dim3(64, 32, 4), dim3(32, 8), 0, stream>>>(qkv, vt);

  // y = P @ V, per batch [2048 x 1024], K truncated by causality
  gemm128_kernel<1><<<dim3(8, 16, 4), 256, 0, stream>>>(
      S, 2048, 2048LL * 2048, vt, 2048, 1024LL * 2048,
      y, 1024, 2048LL * 1024, nullptr, 2048, 1.0f, 2);

  // out = y @ W_proj + b_proj   [8192 x 1024], fp32 out
  gemm128_kernel<0><<<dim3(8, 64, 1), 256, 0, stream>>>(
      y, 1024, 0, wtp, 1024, 0, out, 1024, 0, bp, 1024, 1.0f, 0);
}

// Round 6
// 204.582 us; speedup vs baseline: 1.2933x; 1.0735x over previous
//
#include <hip/hip_runtime.h>

typedef __attribute__((ext_vector_type(8))) short short8;
typedef __attribute__((ext_vector_type(4))) float f32x4;
typedef __attribute__((ext_vector_type(4))) unsigned short ushort4v;

struct DB0 { static constexpr int value = 0; };
struct DB1 { static constexpr int value = 1; };

__device__ __forceinline__ unsigned short f2bf(float f) {
  unsigned int u = __float_as_uint(f);
  u += 0x7fffu + ((u >> 16) & 1u);
  return (unsigned short)(u >> 16);
}
__device__ __forceinline__ float bf2f(unsigned short h) {
  return __uint_as_float(((unsigned int)h) << 16);
}

__device__ __forceinline__ void gload16(const unsigned short* g, unsigned short* l) {
  __builtin_amdgcn_global_load_lds(
      (const __attribute__((address_space(1))) unsigned int*)g,
      (__attribute__((address_space(3))) unsigned int*)l,
      16, 0, 0);
}

template <int OFF>
__device__ __forceinline__ short8 dsr(unsigned a) {
  short8 r;
  asm volatile("ds_read_b128 %0, %1 offset:%2" : "=v"(r) : "v"(a), "n"(OFF));
  return r;
}

__device__ __forceinline__ void bar() {
  asm volatile("" ::: "memory");
  __builtin_amdgcn_s_barrier();
  asm volatile("" ::: "memory");
}

// ---------------- convert x (f32) -> bf16 ----------------
__global__ __launch_bounds__(256) void conv_x_kernel(const float* __restrict__ x,
                                                     unsigned short* __restrict__ xb) {
  int i = blockIdx.x * 256 + threadIdx.x;
  f32x4 v = ((const f32x4*)x)[i];
  ushort4v o;
  o[0] = f2bf(v[0]); o[1] = f2bf(v[1]); o[2] = f2bf(v[2]); o[3] = f2bf(v[3]);
  ((ushort4v*)xb)[i] = o;
}

// ------------- transpose+convert W: f32 [K][N] -> bf16 [N][K] -------------
__global__ __launch_bounds__(256) void transpose_w_kernel(const float* __restrict__ W,
                                                          unsigned short* __restrict__ Wt,
                                                          int K, int N) {
  __shared__ float tile[32][33];
  int n0 = blockIdx.x * 32, k0 = blockIdx.y * 32;
  int tx = threadIdx.x, ty = threadIdx.y;
#pragma unroll
  for (int j = 0; j < 32; j += 8)
    tile[ty + j][tx] = W[(size_t)(k0 + ty + j) * N + n0 + tx];
  __syncthreads();
#pragma unroll
  for (int j = 0; j < 32; j += 8)
    Wt[(size_t)(n0 + ty + j) * K + k0 + tx] = f2bf(tile[tx][ty + j]);
}

// ------- transpose V (bf16 part of qkv) -> vt [B][1024][2048] -------
__global__ __launch_bounds__(256) void transpose_v_kernel(const unsigned short* __restrict__ qkv,
                                                          unsigned short* __restrict__ vt) {
  __shared__ unsigned short tile[32][33];
  int b = blockIdx.z;
  int key0 = blockIdx.x * 32, d0 = blockIdx.y * 32;
  int tx = threadIdx.x, ty = threadIdx.y;
#pragma unroll
  for (int j = 0; j < 32; j += 8)
    tile[ty + j][tx] = qkv[(size_t)(b * 2048 + key0 + ty + j) * 3072 + 2048 + d0 + tx];
  __syncthreads();
#pragma unroll
  for (int j = 0; j < 32; j += 8)
    vt[(size_t)(b * 1024 + d0 + ty + j) * 2048 + key0 + tx] = tile[tx][ty + j];
}

// ---------------- row softmax on S (bf16, in place), rows of 2048 ---------
__global__ __launch_bounds__(256) void softmax_kernel(unsigned short* __restrict__ S) {
  int row = blockIdx.x * 4 + (threadIdx.x >> 6);
  int l = threadIdx.x & 63;
  unsigned short* p = S + (size_t)row * 2048;
  float v[32];
#pragma unroll
  for (int i = 0; i < 4; i++) {
    short8 raw = *(const short8*)&p[(i * 64 + l) * 8];
#pragma unroll
    for (int j = 0; j < 8; j++) v[i * 8 + j] = bf2f((unsigned short)raw[j]);
  }
  float mx = -3e38f;
#pragma unroll
  for (int i = 0; i < 32; i++) mx = fmaxf(mx, v[i]);
#pragma unroll
  for (int off = 1; off < 64; off <<= 1) mx = fmaxf(mx, __shfl_xor(mx, off));
  float s = 0.f;
#pragma unroll
  for (int i = 0; i < 32; i++) { v[i] = exp2f((v[i] - mx) * 1.44269504f); s += v[i]; }
#pragma unroll
  for (int off = 1; off < 64; off <<= 1) s += __shfl_xor(s, off);
  float inv = 1.f / s;
#pragma unroll
  for (int i = 0; i < 4; i++) {
    short8 o;
#pragma unroll
    for (int j = 0; j < 8; j++) o[j] = (short)f2bf(v[i * 8 + j] * inv);
    *(short8*)&p[(i * 64 + l) * 8] = o;
  }
}

// ======== 128x128 GEMM, BK=64 (128B LDS rows), depth-2 ring, 4 waves ======
// st_16x32 swizzle: physical col byte = logical ^ ((row&4)<<3); source is
// pre-swizzled (XOR involution) so gload_lds stays linear (rule 21).
// Schedule (race-free, catalog T3): stage(tt+1)->buf^1; asm ds_read buf;
// lgkmcnt(0); 32 MFMA; vmcnt(0); ONE barrier.
template <int OUTBF>
__global__ __launch_bounds__(256) void gemm128_kernel(
    const unsigned short* __restrict__ A, int lda, long long saz,
    const unsigned short* __restrict__ Bt, int ldb, long long sbz,
    void* __restrict__ Cv, int ldc, long long scz,
    const float* __restrict__ bias, int K, float scale, int causal) {
  // per buf (32KB): A shorts [0,8192) = 128 rows x 64; B shorts [8192,16384)
  __shared__ __align__(16) unsigned short lds[2][16384];

  const int m0 = blockIdx.y * 128, n0 = blockIdx.x * 128;
  const int z = blockIdx.z;
  A += (size_t)z * saz;
  Bt += (size_t)z * sbz;

  const int t = threadIdx.x;
  const int lane = t & 63, wid = t >> 6;
  const int g = lane >> 4, q = lane & 15;
  const int wm = wid >> 1, wn = wid & 1;  // wave tile 64x64

  int NT = K >> 6;
  if (causal == 1) { if (n0 >= m0 + 128) NT = 0; }
  else if (causal == 2) { NT = min(K, m0 + 128) >> 6; }

  f32x4 acc[4][4] = {};

  if (NT > 0) {
    // ---- staging: thread t writes 16B at linear row=(t>>3), chunk=(t&7);
    // source col pre-swizzled: scol = (t&7)*8 ^ ((row&4)?16:0)  [shorts]
    const int scol = ((t & 7) * 8) ^ ((t & 32) >> 1);
    const unsigned short* aS = A + (size_t)(m0 + (t >> 3)) * lda + scol;
    const unsigned short* bS = Bt + (size_t)(n0 + (t >> 3)) * ldb + scol;

    auto stage = [&](int tt) {
      unsigned short* d = &lds[tt & 1][wid * 512];
      const unsigned short* sa = aS + (size_t)tt * 64;
      const unsigned short* sb = bS + (size_t)tt * 64;
      gload16(sa, d);
      gload16(sa + (size_t)32 * lda, d + 2048);
      gload16(sa + (size_t)64 * lda, d + 4096);
      gload16(sa + (size_t)96 * lda, d + 6144);
      gload16(sb, d + 8192);
      gload16(sb + (size_t)32 * ldb, d + 10240);
      gload16(sb + (size_t)64 * ldb, d + 12288);
      gload16(sb + (size_t)96 * ldb, d + 14336);
    };

    // ---- fragment read addresses (bytes); read-side swizzle ^((q&4)<<3)
    const unsigned base =
        (unsigned)(unsigned long long)(__attribute__((address_space(3))) unsigned short*)&lds[0][0];
    const int colA = (g * 16) ^ ((q & 4) << 3);
    const unsigned aaB = base + (unsigned)((wm * 64 + q) * 128 + colA);
    const unsigned bbB = base + 16384u + (unsigned)((wn * 64 + q) * 128 + colA);

    stage(0);
    asm volatile("s_waitcnt vmcnt(0)" ::: "memory");
    bar();

    auto body = [&](auto dbc, int tt) {
      constexpr int DB = decltype(dbc)::value;
      const unsigned aa = aaB + DB * 32768u;
      const unsigned bb = bbB + DB * 32768u;
      if (tt + 1 < NT) stage(tt + 1);
      short8 aq[4][2], bq[4][2];
#pragma unroll
      for (int m = 0; m < 4; m++) {
        aq[m][0] = dsr<0>(aa + m * 2048u);
        aq[m][1] = dsr<64>(aa + m * 2048u);
      }
#pragma unroll
      for (int n = 0; n < 4; n++) {
        bq[n][0] = dsr<0>(bb + n * 2048u);
        bq[n][1] = dsr<64>(bb + n * 2048u);
      }
      asm volatile("s_waitcnt lgkmcnt(0)" ::: "memory");
      __builtin_amdgcn_sched_barrier(0);
      __builtin_amdgcn_s_setprio(1);
#pragma unroll
      for (int ks = 0; ks < 2; ks++)
#pragma unroll
        for (int m = 0; m < 4; m++)
#pragma unroll
          for (int n = 0; n < 4; n++)
            acc[m][n] = __builtin_amdgcn_mfma_f32_16x16x32_bf16(aq[m][ks], bq[n][ks], acc[m][n], 0, 0, 0);
      __builtin_amdgcn_s_setprio(0);
      __builtin_amdgcn_sched_barrier(0);
      asm volatile("s_waitcnt vmcnt(0)" ::: "memory");
      bar();
    };

    int tt = 0;
    for (; tt + 2 <= NT; tt += 2) {
      body(DB0{}, tt);
      body(DB1{}, tt + 1);
    }
    if (tt < NT) body(DB0{}, tt);
  }

  // ---- epilogue ----
#pragma unroll
  for (int n = 0; n < 4; n++) {
    int colg = n0 + wn * 64 + n * 16 + q;
    float bv = bias ? bias[colg] : 0.f;
#pragma unroll
    for (int m = 0; m < 4; m++) {
      int rowb = m0 + wm * 64 + m * 16 + g * 4;
#pragma unroll
      for (int r = 0; r < 4; r++) {
        float val = acc[m][n][r] * scale + bv;
        if (causal == 1 && colg > rowb + r) val = -1e30f;
        if (OUTBF) {
          ((unsigned short*)Cv)[(size_t)z * scz + (size_t)(rowb + r) * ldc + colg] = f2bf(val);
        } else {
          ((float*)Cv)[(size_t)z * scz + (size_t)(rowb + r) * ldc + colg] = val;
        }
      }
    }
  }
}

extern "C" void kernel_launch(void* const* d_in, const int* in_sizes, int n_in,
                              void* d_out, int out_size, void* d_ws, size_t ws_size,
                              hipStream_t stream) {
  const float* x  = (const float*)d_in[0];
  const float* Wa = (const float*)d_in[1];
  const float* ba = (const float*)d_in[2];
  const float* Wp = (const float*)d_in[3];
  const float* bp = (const float*)d_in[4];
  float* out = (float*)d_out;

  char* ws = (char*)d_ws;
  unsigned short* qkv = (unsigned short*)(ws);                 // 50331648
  unsigned short* xb  = (unsigned short*)(ws + 50331648);      // 16777216
  unsigned short* vt  = (unsigned short*)(ws + 50331648);      // overlay xb
  unsigned short* wta = (unsigned short*)(ws + 67108864);      // 6291456
  unsigned short* S   = (unsigned short*)(ws + 73400320);      // 33554432
  unsigned short* y   = (unsigned short*)(ws + 106954752);     // 16777216
  unsigned short* wtp = (unsigned short*)(ws + 123731968);     // 2097152

  conv_x_kernel<<<8192, 256, 0, stream>>>(x, xb);
  transpose_w_kernel<<<dim3(96, 32), dim3(32, 8), 0, stream>>>(Wa, wta, 1024, 3072);
  transpose_w_kernel<<<dim3(32, 32), dim3(32, 8), 0, stream>>>(Wp, wtp, 1024, 1024);

  // qkv = x @ W_attn + b_attn   [8192 x 3072]
  gemm128_kernel<1><<<dim3(24, 64, 1), 256, 0, stream>>>(
      xb, 1024, 0, wta, 1024, 0, qkv, 3072, 0, ba, 1024, 1.0f, 0);

  // S = Q @ K^T * 0.125 (causal masked), per batch [2048 x 2048]
  gemm128_kernel<1><<<dim3(16, 16, 4), 256, 0, stream>>>(
      qkv, 3072, 2048LL * 3072, qkv + 1024, 3072, 2048LL * 3072,
      S, 2048, 2048LL * 2048, nullptr, 1024, 0.125f, 1);

  softmax_kernel<<<2048, 256, 0, stream>>>(S);

  transpose_v_kernel<<<dim3(64, 32, 4), dim3(32, 8), 0, stream>>>(qkv, vt);

  // y = P @ V, per batch [2048 x 1024], K truncated by causality
  gemm128_kernel<1><<<dim3(8, 16, 4), 256, 0, stream>>>(
      S, 2048, 2048LL * 2048, vt, 2048, 1024LL * 2048,
      y, 1024, 2048LL * 1024, nullptr, 2048, 1.0f, 2);

  // out = y @ W_proj + b_proj   [8192 x 1024], fp32 out
  gemm128_kernel<0><<<dim3(8, 64, 1), 256, 0, stream>>>(
      y, 1024, 0, wtp, 1024, 0, out, 1024, 0, bp, 1024, 1.0f, 0);
}